// Round 1
// 557.473 us; speedup vs baseline: 1.1760x; 1.1760x over previous
//
#include <hip/hip_runtime.h>
#include <stdint.h>

__device__ __forceinline__ float bf2f(uint32_t v) { return __uint_as_float(v << 16); }
__device__ __forceinline__ uint32_t f2bf(float f) {
  uint32_t u = __float_as_uint(f);
  return (u + 0x7fffu + ((u >> 16) & 1u)) >> 16;  // RNE
}

// jax.image.resize bilinear 16->32 closed form (edge renorm == clamp)
__device__ __forceinline__ void interp_coord(int p, int& i0, int& i1, float& f) {
  if (p == 0)       { i0 = 0;  i1 = 0;  f = 0.f; }
  else if (p == 31) { i0 = 15; i1 = 15; f = 0.f; }
  else if (p & 1)   { i0 = (p - 1) >> 1; i1 = i0 + 1; f = 0.25f; }
  else              { i0 = (p >> 1) - 1; i1 = i0 + 1; f = 0.75f; }
}

typedef short bf16x8 __attribute__((ext_vector_type(8)));
typedef float f32x4 __attribute__((ext_vector_type(4)));

// ---------------------------------------------------------------------------
// Kernel A: two-level Haar DWT.  x (32,128,128,128) f32 -> bands bf16
// layout [k][p=h*32+w][b][i].  (unchanged — near coalesced-BW floor)
// ---------------------------------------------------------------------------
__global__ __launch_bounds__(256) void dwt_kernel(const float* __restrict__ x,
                                                  uint16_t* __restrict__ bands) {
  __shared__ uint16_t tile[4 * 32 * 34];  // [k][w][c pad 34], 8.7 KB
  const int bid = blockIdx.x;
  const int cg4 = bid & 3;          // 32-channel group
  const int h   = (bid >> 2) & 31;  // output row
  const int b   = bid >> 7;         // batch
  const int t   = threadIdx.x;
  const int w   = t & 31;           // output col
  const int cl  = t >> 5;           // 0..7
#pragma unroll
  for (int cc = 0; cc < 4; ++cc) {
    const int c = cl + (cc << 3);   // 0..31 local channel
    const float* xc = x + (((size_t)(b << 7) + (cg4 << 5) + c) << 14) + (h << 9) + (w << 2);
    float4 r0 = *(const float4*)(xc);
    float4 r1 = *(const float4*)(xc + 128);
    float4 r2 = *(const float4*)(xc + 256);
    float4 r3 = *(const float4*)(xc + 384);
    float S00 = r0.x + r0.y + r1.x + r1.y;
    float S01 = r0.z + r0.w + r1.z + r1.w;
    float S10 = r2.x + r2.y + r3.x + r3.y;
    float S11 = r2.z + r2.w + r3.z + r3.w;
    tile[(0 * 32 + w) * 34 + c] = (uint16_t)f2bf(0.25f * (S00 + S01 + S10 + S11));  // ll
    tile[(1 * 32 + w) * 34 + c] = (uint16_t)f2bf(0.25f * (S00 - S01 + S10 - S11));  // lh
    tile[(2 * 32 + w) * 34 + c] = (uint16_t)f2bf(0.25f * (S00 + S01 - S10 - S11));  // hl
    tile[(3 * 32 + w) * 34 + c] = (uint16_t)f2bf(0.25f * (S00 - S01 - S10 + S11));  // hh
  }
  __syncthreads();
  const uint32_t* tl = (const uint32_t*)tile;
  uint32_t* bo = (uint32_t*)bands;
#pragma unroll
  for (int j = 0; j < 8; ++j) {
    const int idx = t + (j << 8);   // 0..2047
    const int k   = idx >> 9;
    const int rem = idx & 511;
    const int w2  = rem >> 4;
    const int qq  = rem & 15;       // i-pair within 32-ch group
    const uint32_t v = tl[(k * 32 + w2) * 17 + qq];
    bo[(((size_t)(k << 10) + (h << 5) + w2) << 11) + (b << 6) + (cg4 << 4) + qq] = v;
  }
}

// ---------------------------------------------------------------------------
// Kernel B: repack base weights to bf16 wr[k][yx][o*128+i]  (33.5 MB, in
// d_out scratch).  Replaces the 134 MB interpolated-W32 materialization:
// interpolation is now fused into the GEMM.  Block = (k, o).
// ---------------------------------------------------------------------------
__global__ __launch_bounds__(256) void wrepack_kernel(const float* __restrict__ w1,
                                                      const float* __restrict__ w2,
                                                      const float* __restrict__ w3,
                                                      const float* __restrict__ w4,
                                                      uint16_t* __restrict__ wr) {
  __shared__ uint16_t L[64 * 262];  // [i_local][yx pad 262], 33.5 KB
  const int bid = blockIdx.x;       // 512
  const int k = bid >> 7;
  const int o = bid & 127;
  const float* src = (k == 0) ? w1 : (k == 1) ? w2 : (k == 2) ? w3 : w4;
  const int t = threadIdx.x;
  uint32_t* Lu = (uint32_t*)L;
  for (int ih = 0; ih < 2; ++ih) {    // two halves of i (64 each)
    if (ih) __syncthreads();          // protect LDS reuse
#pragma unroll
    for (int j = 0; j < 16; ++j) {
      const int ridx = t + (j << 8);  // 0..4095
      const int il = ridx >> 6;       // 0..63 local i
      const int x4 = ridx & 63;       // float4 within 256 yx
      float4 v = *(const float4*)(src + (((size_t)((ih * 64 + il) * 128 + o)) << 8) + (x4 << 2));
      Lu[il * 131 + (x4 << 1)]     = f2bf(v.x) | (f2bf(v.y) << 16);
      Lu[il * 131 + (x4 << 1) + 1] = f2bf(v.z) | (f2bf(v.w) << 16);
    }
    __syncthreads();
    // emit: for each yx, i-pairs -> 128B coalesced runs
#pragma unroll
    for (int j = 0; j < 32; ++j) {
      const int oidx = t + (j << 8);  // 0..8191
      const int yx = oidx >> 5;       // 0..255
      const int q  = oidx & 31;       // i-pair within this 64-i half
      const uint32_t lo = L[(q << 1) * 262 + yx];
      const uint32_t hi = L[((q << 1) + 1) * 262 + yx];
      uint32_t* dst = (uint32_t*)wr + (((size_t)(k << 8) + yx) << 13) + (o << 6) + (ih << 5) + q;
      *dst = lo | (hi << 16);
    }
  }
}

// ---------------------------------------------------------------------------
// Kernel C: per (p,k) 32x128x128 GEMM via MFMA bf16, with fused bilinear
// weight interpolation.  Wt[o][i] built in LDS from 4 contiguous wr rows
// (L2/L3-hot); A-fragments read straight from global (8 KB slice, L1-hot).
// D bounced through LDS for coalesced bf16 stores to ws2[k][p][b][o].
// ---------------------------------------------------------------------------
__global__ __launch_bounds__(256) void gemm_kernel(const uint16_t* __restrict__ bands,
                                                   const uint16_t* __restrict__ wr,
                                                   uint16_t* __restrict__ ws2) {
  __shared__ uint16_t Wt[128 * 136];  // [o][i pad 136], 34.8 KB -> 4 blocks/CU
  const int bid = blockIdx.x;
  const int k = bid & 3;
  const int p = bid >> 2;
  const int t = threadIdx.x;
  // ---- fused interp: build Wt[o][i] ----
  const int py = p >> 5, px = p & 31;
  int y0, y1, x0, x1; float fy, fx;
  interp_coord(py, y0, y1, fy);
  interp_coord(px, x0, x1, fx);
  const float c00 = (1.f - fy) * (1.f - fx), c01 = (1.f - fy) * fx;
  const float c10 = fy * (1.f - fx),         c11 = fy * fx;
  const uint16_t* wk = wr + ((size_t)k << 22);  // k * 256 * 16384
  const uint4* rA = (const uint4*)(wk + (((size_t)(y0 << 4) + x0) << 14));
  const uint4* rB = (const uint4*)(wk + (((size_t)(y0 << 4) + x1) << 14));
  const uint4* rC = (const uint4*)(wk + (((size_t)(y1 << 4) + x0) << 14));
  const uint4* rD = (const uint4*)(wk + (((size_t)(y1 << 4) + x1) << 14));
  uint32_t* Wtu = (uint32_t*)Wt;
#pragma unroll
  for (int j = 0; j < 8; ++j) {
    const int fi = t + (j << 8);   // uint4 index 0..2047
    const int o  = fi >> 4;
    const int i8 = fi & 15;        // x8 elems
    const uint4 a = rA[fi], b = rB[fi], c = rC[fi], d = rD[fi];
    uint32_t ou[4];
#pragma unroll
    for (int cc = 0; cc < 4; ++cc) {
      const uint32_t ua = (&a.x)[cc], ub = (&b.x)[cc], uc = (&c.x)[cc], ud = (&d.x)[cc];
      float lo = c00 * __uint_as_float(ua << 16) + c01 * __uint_as_float(ub << 16)
               + c10 * __uint_as_float(uc << 16) + c11 * __uint_as_float(ud << 16);
      float hi = c00 * __uint_as_float(ua & 0xffff0000u) + c01 * __uint_as_float(ub & 0xffff0000u)
               + c10 * __uint_as_float(uc & 0xffff0000u) + c11 * __uint_as_float(ud & 0xffff0000u);
      ou[cc] = f2bf(lo) | (f2bf(hi) << 16);
    }
    *(uint4*)(Wtu + o * 68 + (i8 << 2)) = make_uint4(ou[0], ou[1], ou[2], ou[3]);
  }
  __syncthreads();
  // ---- MFMA 32(b) x 128(o) x 128(i); wave w owns o in [32w, 32w+32) ----
  const int wv = t >> 6;
  const int l  = t & 63;
  const int lr = l & 15;           // row-in-tile
  const int lk = (l >> 4) << 3;    // k-offset within 32-chunk: 0,8,16,24
  const uint16_t* gA = bands + (((size_t)(k << 10) + p) << 12);
  bf16x8 af[2][4], bg[2][4];
#pragma unroll
  for (int s = 0; s < 4; ++s) {
#pragma unroll
    for (int m = 0; m < 2; ++m)
      af[m][s] = *(const bf16x8*)(gA + (((m << 4) + lr) << 7) + (s << 5) + lk);
#pragma unroll
    for (int n = 0; n < 2; ++n)
      bg[n][s] = *(const bf16x8*)(&Wt[((wv << 5) + (n << 4) + lr) * 136 + (s << 5) + lk]);
  }
  f32x4 acc[2][2] = {};
#pragma unroll
  for (int s = 0; s < 4; ++s)
#pragma unroll
    for (int m = 0; m < 2; ++m)
#pragma unroll
      for (int n = 0; n < 2; ++n)
        acc[m][n] = __builtin_amdgcn_mfma_f32_16x16x32_bf16(af[m][s], bg[n][s], acc[m][n], 0, 0, 0);
  __syncthreads();
  // ---- D -> LDS (reuse Wt as Ds[32][136]) -> coalesced global ----
  uint16_t* Ds = Wt;
#pragma unroll
  for (int m = 0; m < 2; ++m)
#pragma unroll
    for (int n = 0; n < 2; ++n)
#pragma unroll
      for (int r = 0; r < 4; ++r) {
        const int b_ = (m << 4) + ((l >> 4) << 2) + r;          // batch row
        const int o_ = (wv << 5) + (n << 4) + lr;               // out channel
        Ds[b_ * 136 + o_] = (uint16_t)f2bf(acc[m][n][r]);
      }
  __syncthreads();
  uint32_t* outp = (uint32_t*)(ws2 + (((size_t)(k << 10) + p) << 12));
  const uint32_t* Dsu = (const uint32_t*)Ds;
#pragma unroll
  for (int j = 0; j < 8; ++j) {
    const int idx = t + (j << 8);   // 0..2047 u32
    const int b_ = idx >> 6, c_ = idx & 63;
    outp[idx] = Dsu[b_ * 68 + c_];
  }
}

// ---------------------------------------------------------------------------
// Kernel D: fused idwt + zero-band 2x upsample.  (unchanged)
// ---------------------------------------------------------------------------
__global__ __launch_bounds__(256) void idwt_kernel(const uint16_t* __restrict__ ws2,
                                                   float* __restrict__ out) {
  __shared__ uint16_t Ls[4 * 32 * 130];  // [k][w][o pad 130], 33.3 KB
  const int bid = blockIdx.x;
  const int b = bid >> 5;
  const int h = bid & 31;
  const int t = threadIdx.x;
  const uint32_t* su = (const uint32_t*)ws2;
  uint32_t* Lu = (uint32_t*)Ls;
#pragma unroll 4
  for (int j = 0; j < 32; ++j) {
    const int idx = t + (j << 8);   // 0..8191
    const int kw = idx >> 6;        // k*32+w
    const int uo = idx & 63;
    const int k = kw >> 5, w = kw & 31;
    const uint32_t v = su[(((size_t)(k << 10) + (h << 5) + w) << 11) + (b << 6) + uo];
    Lu[kw * 65 + uo] = v;
  }
  __syncthreads();
  const int x4 = t & 31;   // w, and the out float4 index
  const int og = t >> 5;
  for (int pp = 0; pp < 16; ++pp) {
    const int o = (pp << 3) + og;
    const float A = bf2f(Ls[(0 * 32 + x4) * 130 + o]);
    const float B = bf2f(Ls[(1 * 32 + x4) * 130 + o]);
    const float C = bf2f(Ls[(2 * 32 + x4) * 130 + o]);
    const float D = bf2f(Ls[(3 * 32 + x4) * 130 + o]);
    const float E = A + B, F = A - B, G = C + D, Hh = C - D;
    const float vL0 = 0.25f * (E + G),  vR0 = 0.25f * (F + Hh);  // rows 0,1
    const float vL1 = 0.25f * (E - G),  vR1 = 0.25f * (F - Hh);  // rows 2,3
    float* ob = out + (((size_t)(b << 7) + o) << 14) + (h << 9) + (x4 << 2);
    float4 top = make_float4(vL0, vL0, vR0, vR0);
    float4 bot = make_float4(vL1, vL1, vR1, vR1);
    *(float4*)(ob)       = top;
    *(float4*)(ob + 128) = top;
    *(float4*)(ob + 256) = bot;
    *(float4*)(ob + 384) = bot;
  }
}

extern "C" void kernel_launch(void* const* d_in, const int* in_sizes, int n_in,
                              void* d_out, int out_size, void* d_ws, size_t ws_size,
                              hipStream_t stream) {
  const float* x  = (const float*)d_in[0];
  const float* w1 = (const float*)d_in[1];
  const float* w2 = (const float*)d_in[2];
  const float* w3 = (const float*)d_in[3];
  const float* w4 = (const float*)d_in[4];

  uint16_t* bands = (uint16_t*)d_ws;            // 4*1024*4096 bf16 = 33.5 MB
  uint16_t* ws2   = bands + (size_t)16777216;   // 4*1024*4096 bf16 = 33.5 MB
  // wr (33.5 MB bf16 repacked weights) lives in d_out as scratch; idwt_kernel
  // rewrites all of d_out afterwards (stream-ordered, no overlap with reads).
  uint16_t* wr = (uint16_t*)d_out;

  wrepack_kernel<<<512, 256, 0, stream>>>(w1, w2, w3, w4, wr);
  dwt_kernel<<<4096, 256, 0, stream>>>(x, bands);
  gemm_kernel<<<4096, 256, 0, stream>>>(bands, wr, ws2);
  idwt_kernel<<<1024, 256, 0, stream>>>(ws2, (float*)d_out);
}